// Round 2
// baseline (145.452 us; speedup 1.0000x reference)
//
#include <hip/hip_runtime.h>
#include <hip/hip_bf16.h>
#include <float.h>

#define B_ 16
#define D_ 64
#define L_ 8192
#define K_ 512

#define TILE_TOKENS 64
#define NBLOCKS 256
#define TILES_PER_BLOCK 8   // 2048 tiles / 256 blocks

// Persistent-block VQ matcher, fp32 in/out.
// Block = 512 threads = 8 waves; 1 block/CU (151 KB LDS).
// Wave w: tokens w*8..w*8+7; lane owns codes {4*lane..4*lane+3} u {256+4*lane..}.
__global__ __launch_bounds__(512, 2)
void vq_match_kernel(const float* __restrict__ X, const float* __restrict__ E,
                     float* __restrict__ out_emb, float* __restrict__ out_idx)
{
    __shared__ float e_lds[D_][K_];       // 128 KB codebook
    __shared__ float esq[K_];             // 2 KB
    __shared__ float x_lds[D_][68];       // pad 68: conflict-lite column reads
    __shared__ float xsq[TILE_TOKENS];
    __shared__ int   bestk[TILE_TOKENS];

    const int tid  = threadIdx.x;
    const int lane = tid & 63;
    const int wave = tid >> 6;

    // ---- stage full codebook E (D x K), coalesced float4 ----
    {
        int d0 = tid >> 7;          // 0..3
        int k4 = (tid & 127) << 2;  // 0..508
        #pragma unroll
        for (int it = 0; it < 16; ++it) {
            int d = it * 4 + d0;
            *reinterpret_cast<float4*>(&e_lds[d][k4]) =
                *reinterpret_cast<const float4*>(E + d * K_ + k4);
        }
    }
    __syncthreads();
    // ---- e_sq[k]: rounded squares, strictly sequential over d (np axis-0 reduce) ----
    {
        float v = e_lds[0][tid];
        float s = v * v;
        #pragma unroll
        for (int d = 1; d < D_; ++d) { float w = e_lds[d][tid]; s += w * w; }
        esq[tid] = s;
    }

    for (int t = 0; t < TILES_PER_BLOCK; ++t) {
        int tile = blockIdx.x * TILES_PER_BLOCK + t;
        int b  = tile >> 7;            // tile / 128
        int l0 = (tile & 127) << 6;    // (tile % 128) * 64

        __syncthreads();  // esq ready (iter 0); x_lds/xsq/bestk reuse safe

        // ---- stage X tile (64 tokens x 64 dims), coalesced along l ----
        {
            int i  = tid & 63;
            int dd = tid >> 6;  // 0..7
            const float* base = X + ((size_t)b * D_) * L_ + l0 + i;
            #pragma unroll
            for (int r = 0; r < 8; ++r) {
                int d = dd * 8 + r;
                x_lds[d][i] = base[(size_t)d * L_];
            }
        }
        __syncthreads();

        // ---- x_sq per token: numpy pairwise (8 accumulators, rounded squares) ----
        if (tid < TILE_TOKENS) {
            float r[8];
            #pragma unroll
            for (int j = 0; j < 8; ++j) { float v = x_lds[j][tid]; r[j] = v * v; }
            #pragma unroll
            for (int i8 = 8; i8 < 64; i8 += 8)
                #pragma unroll
                for (int j = 0; j < 8; ++j) { float v = x_lds[i8 + j][tid]; r[j] += v * v; }
            xsq[tid] = ((r[0] + r[1]) + (r[2] + r[3])) + ((r[4] + r[5]) + (r[6] + r[7]));
        }
        __syncthreads();

        // ---- dot products: acc[token][code], sequential-d FMA (matches sgemm) ----
        float acc[8][8];
        #pragma unroll
        for (int i = 0; i < 8; ++i)
            #pragma unroll
            for (int j = 0; j < 8; ++j) acc[i][j] = 0.f;

        const int kb0   = lane << 2;          // codes kb0..kb0+3
        const int kb1   = 256 + (lane << 2);  // codes kb1..kb1+3
        const int ibase = wave << 3;

        #pragma unroll 8
        for (int d = 0; d < D_; ++d) {
            float4 e0 = *reinterpret_cast<const float4*>(&e_lds[d][kb0]);
            float4 e1 = *reinterpret_cast<const float4*>(&e_lds[d][kb1]);
            float4 x0 = *reinterpret_cast<const float4*>(&x_lds[d][ibase]);     // uniform bcast
            float4 x1 = *reinterpret_cast<const float4*>(&x_lds[d][ibase + 4]);
            float xv[8] = {x0.x, x0.y, x0.z, x0.w, x1.x, x1.y, x1.z, x1.w};
            float ev[8] = {e0.x, e0.y, e0.z, e0.w, e1.x, e1.y, e1.z, e1.w};
            #pragma unroll
            for (int i = 0; i < 8; ++i)
                #pragma unroll
                for (int j = 0; j < 8; ++j)
                    acc[i][j] = fmaf(xv[i], ev[j], acc[i][j]);
        }

        // ---- scores + argmin: (x_sq - 2*dot) + e_sq, ties -> lowest k ----
        float q[8];
        {
            float4 q0 = *reinterpret_cast<const float4*>(&esq[kb0]);
            float4 q1 = *reinterpret_cast<const float4*>(&esq[kb1]);
            q[0]=q0.x; q[1]=q0.y; q[2]=q0.z; q[3]=q0.w;
            q[4]=q1.x; q[5]=q1.y; q[6]=q1.z; q[7]=q1.w;
        }
        #pragma unroll
        for (int i = 0; i < 8; ++i) {
            float xs = xsq[ibase + i];
            float bv = FLT_MAX;
            int   bk = 0;
            #pragma unroll
            for (int j = 0; j < 8; ++j) {
                int   k = (j < 4) ? (kb0 + j) : (kb1 + j - 4);  // ascending within lane
                float s = (xs - 2.0f * acc[i][j]) + q[j];
                if (s < bv) { bv = s; bk = k; }                  // strict < keeps first min
            }
            #pragma unroll
            for (int off = 1; off < 64; off <<= 1) {
                float ov = __shfl_xor(bv, off, 64);
                int   ok = __shfl_xor(bk, off, 64);
                if (ov < bv || (ov == bv && ok < bk)) { bv = ov; bk = ok; }
            }
            if (lane == 0) bestk[ibase + i] = bk;
        }
        __syncthreads();

        // ---- gather + write fp32 outputs, float4 (4 tokens) per store ----
        {
            int qd = tid & 15;   // token quad 0..15
            int dg = tid >> 4;   // 0..31
            int i4 = qd * 4;
            int k0 = bestk[i4], k1 = bestk[i4 + 1], k2 = bestk[i4 + 2], k3 = bestk[i4 + 3];
            size_t obase = ((size_t)b * D_) * L_ + l0 + i4;
            #pragma unroll
            for (int h = 0; h < 2; ++h) {
                int d = dg + h * 32;
                float4 v;
                v.x = e_lds[d][k0]; v.y = e_lds[d][k1];
                v.z = e_lds[d][k2]; v.w = e_lds[d][k3];
                *reinterpret_cast<float4*>(out_emb + obase + (size_t)d * L_) = v;
            }
        }
        if (tid < TILE_TOKENS) {
            out_idx[(size_t)b * L_ + l0 + tid] = (float)bestk[tid];
        }
    }
}

extern "C" void kernel_launch(void* const* d_in, const int* in_sizes, int n_in,
                              void* d_out, int out_size, void* d_ws, size_t ws_size,
                              hipStream_t stream) {
    const float* X = (const float*)d_in[0];   // (B, D, L) fp32
    const float* E = (const float*)d_in[1];   // (D, K) fp32
    float* out     = (float*)d_out;
    float* out_emb = out;                                 // B*D*L fp32
    float* out_idx = out + (size_t)B_ * D_ * L_;          // B*L fp32
    vq_match_kernel<<<NBLOCKS, 512, 0, stream>>>(X, E, out_emb, out_idx);
}